// Round 2
// baseline (399.988 us; speedup 1.0000x reference)
//
#include <hip/hip_runtime.h>

#define NPIX   768
#define PP     256
#define NTERMS 128
#define EPSF   1e-15f

typedef float f32x4 __attribute__((ext_vector_type(4)));

#define NV4   (NPIX * NPIX / 4)   // 147456 f32x4 per 768x768 plane

// ---------------------------------------------------------------------------
// Kernel 1: W[t] = sum_n basis[n][t] * coeffs[n]
//
// DECISIVE-EXPERIMENT SHAPE (round 2): canonical globally-contiguous
// streaming reduction.
//   - thread-per-t: thread gid owns f32x4 index t; 576 blocks x 256 thr
//     cover NV4 exactly. A wave's 64 lanes read one contiguous 1 KB line;
//     consecutive blocks read consecutive lines -> at any instant the chip
//     sweeps a contiguous ~8-plane (~19 MB) window through basis, the same
//     address-pattern class as the 80%-peak fill.
//   - unroll 8 planes: 8 outstanding 16B loads/lane = 8 KB/wave in flight;
//     ~9 waves/CU -> 72 KB/CU >> ~9 KB needed at ~900 cy HBM latency.
//   - NO nontemporal hint (present in all prior variants; the one shared
//     suspect for the occupancy-invariant 1.7 TB/s ceiling if (B2)).
//   - two accumulators to break the FMA dependence chain.
// ---------------------------------------------------------------------------
__global__ __launch_bounds__(256) void latent_kernel(
    const float* __restrict__ basis,
    const float* __restrict__ coeffs,
    float* __restrict__ W)
{
    __shared__ float sc[NTERMS];
    if (threadIdx.x < NTERMS) sc[threadIdx.x] = coeffs[threadIdx.x];
    __syncthreads();

    const int t = blockIdx.x * 256 + threadIdx.x;      // 0 .. NV4-1
    const f32x4* __restrict__ b4 = (const f32x4*)basis + t;

    f32x4 acc0 = {0.f, 0.f, 0.f, 0.f};
    f32x4 acc1 = {0.f, 0.f, 0.f, 0.f};

    #pragma unroll 1
    for (int n = 0; n < NTERMS; n += 8) {
        f32x4 v0 = b4[(long)(n + 0) * NV4];
        f32x4 v1 = b4[(long)(n + 1) * NV4];
        f32x4 v2 = b4[(long)(n + 2) * NV4];
        f32x4 v3 = b4[(long)(n + 3) * NV4];
        f32x4 v4 = b4[(long)(n + 4) * NV4];
        f32x4 v5 = b4[(long)(n + 5) * NV4];
        f32x4 v6 = b4[(long)(n + 6) * NV4];
        f32x4 v7 = b4[(long)(n + 7) * NV4];

        const float c0 = sc[n + 0];
        const float c1 = sc[n + 1];
        const float c2 = sc[n + 2];
        const float c3 = sc[n + 3];
        const float c4 = sc[n + 4];
        const float c5 = sc[n + 5];
        const float c6 = sc[n + 6];
        const float c7 = sc[n + 7];

        acc0.x = fmaf(v0.x, c0, acc0.x); acc0.y = fmaf(v0.y, c0, acc0.y);
        acc0.z = fmaf(v0.z, c0, acc0.z); acc0.w = fmaf(v0.w, c0, acc0.w);
        acc1.x = fmaf(v1.x, c1, acc1.x); acc1.y = fmaf(v1.y, c1, acc1.y);
        acc1.z = fmaf(v1.z, c1, acc1.z); acc1.w = fmaf(v1.w, c1, acc1.w);
        acc0.x = fmaf(v2.x, c2, acc0.x); acc0.y = fmaf(v2.y, c2, acc0.y);
        acc0.z = fmaf(v2.z, c2, acc0.z); acc0.w = fmaf(v2.w, c2, acc0.w);
        acc1.x = fmaf(v3.x, c3, acc1.x); acc1.y = fmaf(v3.y, c3, acc1.y);
        acc1.z = fmaf(v3.z, c3, acc1.z); acc1.w = fmaf(v3.w, c3, acc1.w);
        acc0.x = fmaf(v4.x, c4, acc0.x); acc0.y = fmaf(v4.y, c4, acc0.y);
        acc0.z = fmaf(v4.z, c4, acc0.z); acc0.w = fmaf(v4.w, c4, acc0.w);
        acc1.x = fmaf(v5.x, c5, acc1.x); acc1.y = fmaf(v5.y, c5, acc1.y);
        acc1.z = fmaf(v5.z, c5, acc1.z); acc1.w = fmaf(v5.w, c5, acc1.w);
        acc0.x = fmaf(v6.x, c6, acc0.x); acc0.y = fmaf(v6.y, c6, acc0.y);
        acc0.z = fmaf(v6.z, c6, acc0.z); acc0.w = fmaf(v6.w, c6, acc0.w);
        acc1.x = fmaf(v7.x, c7, acc1.x); acc1.y = fmaf(v7.y, c7, acc1.y);
        acc1.z = fmaf(v7.z, c7, acc1.z); acc1.w = fmaf(v7.w, c7, acc1.w);
    }

    f32x4* __restrict__ W4 = (f32x4*)W;
    W4[t] = acc0 + acc1;
}

// ---------------------------------------------------------------------------
// Closed-form CLIMB area for one 3x3 patch.
// f[m], m = q*3+s  corresponds to sample at x = s/2, y = q/2.
// Least-squares plane fit (regressors orthogonal after centering):
//   a = (sum_{s=2} - sum_{s=0}) / 3
//   b = (sum_{q=2} - sum_{q=0}) / 3
//   c = mean - 0.5*(a+b)
// ---------------------------------------------------------------------------
__device__ __forceinline__ float climb_area(const float f[9])
{
    float sum = 0.f;
    #pragma unroll
    for (int m = 0; m < 9; ++m) sum += f[m];
    float mean = sum * (1.f / 9.f);

    float a = (f[2] + f[5] + f[8] - f[0] - f[3] - f[6]) * (1.f / 3.f);
    float b = (f[6] + f[7] + f[8] - f[0] - f[1] - f[2]) * (1.f / 3.f);
    float c = mean - 0.5f * (a + b);

    if (a == 0.f) a = EPSF;
    if (b == 0.f) b = EPSF;
    if (c == 0.f) c = EPSF;

    float x1 = (-b - c) / a;
    float x2 = -c / a;
    float lo = fminf(x1, x2);
    float hi = fmaxf(x1, x2);
    x1 = fmaxf(lo, 0.f);
    x2 = fminf(hi, 1.f);

    float cb = -c / b;
    float ab = 0.5f * (a / b);
    float d = x1 + cb * x2 - ab * x2 * x2 - cb * x1 + ab * x1 * x1;

    d = (d >= 0.5f) ? d : 1.f - d;
    d = (mean >= 0.f) ? d : 1.f - d;

    bool allpos = true, allnp = true, anyz = false;
    #pragma unroll
    for (int m = 0; m < 9; ++m) {
        allpos = allpos && (f[m] > 0.f);
        allnp  = allnp  && (f[m] <= 0.f);
        anyz   = anyz   || (f[m] == 0.f);
    }
    if (allpos) d = 1.f;
    if (allnp)  d = 0.f;
    if (anyz)   d = (d > 0.f) ? 1.f : 0.f;

    return fminf(fmaxf(d, 0.f), 1.f);
}

// ---------------------------------------------------------------------------
// Kernel 2: one thread per output pixel (r,p), t = r*256 + p.
//   f[q*3+s] = W[3r+s][3p+q]
//   out = area * ideal_wavel / 2     (pi cancels)
// W is 2.36 MB, L2/L3-resident right after kernel 1.
// ---------------------------------------------------------------------------
__global__ __launch_bounds__(256) void climb_kernel(
    const float* __restrict__ W,
    const float* __restrict__ wavel,
    float* __restrict__ out)
{
    const int t = blockIdx.x * 256 + threadIdx.x;   // 0 .. 65535
    const int r = t >> 8;
    const int p = t & 255;

    const float* __restrict__ base = W + (3 * r) * NPIX + 3 * p;
    float f[9];
    #pragma unroll
    for (int s = 0; s < 3; ++s)
        #pragma unroll
        for (int q = 0; q < 3; ++q)
            f[q * 3 + s] = base[s * NPIX + q];

    out[t] = climb_area(f) * 0.5f * wavel[0];
}

// ---------------------------------------------------------------------------
// Fallback: fully fused (used only if d_ws can't hold W). Same math,
// basis read directly with 9 scalar loads per term (aggregate-coalesced).
// ---------------------------------------------------------------------------
__global__ __launch_bounds__(256) void fused_kernel(
    const float* __restrict__ basis,
    const float* __restrict__ coeffs,
    const float* __restrict__ wavel,
    float* __restrict__ out)
{
    __shared__ float sc[NTERMS];
    if (threadIdx.x < NTERMS) sc[threadIdx.x] = coeffs[threadIdx.x];
    __syncthreads();

    const int t = blockIdx.x * 256 + threadIdx.x;
    const int r = t >> 8;
    const int p = t & 255;

    const float* __restrict__ base = basis + (3 * r) * NPIX + 3 * p;
    float f[9];
    #pragma unroll
    for (int m = 0; m < 9; ++m) f[m] = 0.f;

    for (int n = 0; n < NTERMS; ++n) {
        const float* __restrict__ bn = base + (long)n * NPIX * NPIX;
        float cn = sc[n];
        #pragma unroll
        for (int s = 0; s < 3; ++s)
            #pragma unroll
            for (int q = 0; q < 3; ++q)
                f[q * 3 + s] = fmaf(bn[s * NPIX + q], cn, f[q * 3 + s]);
    }

    out[t] = climb_area(f) * 0.5f * wavel[0];
}

extern "C" void kernel_launch(void* const* d_in, const int* in_sizes, int n_in,
                              void* d_out, int out_size, void* d_ws, size_t ws_size,
                              hipStream_t stream)
{
    const float* basis  = (const float*)d_in[0];  // 128*768*768 f32
    const float* coeffs = (const float*)d_in[1];  // 128 f32
    const float* wavel  = (const float*)d_in[2];  // 1 f32
    float* out = (float*)d_out;                   // 256*256 f32

    const size_t w_bytes = (size_t)NPIX * NPIX * sizeof(float);  // 2.36 MB
    if (ws_size >= w_bytes) {
        float* W = (float*)d_ws;
        latent_kernel<<<NV4 / 256, 256, 0, stream>>>(basis, coeffs, W);
        climb_kernel<<<(PP * PP) / 256, 256, 0, stream>>>(W, wavel, out);
    } else {
        fused_kernel<<<(PP * PP) / 256, 256, 0, stream>>>(basis, coeffs, wavel, out);
    }
}